// Round 1
// baseline (389.031 us; speedup 1.0000x reference)
//
#include <hip/hip_runtime.h>

#define B_ 2
#define N_ 10000
#define E_ 150000
#define C_ 256
#define M_EDGE (B_*E_)   // 300000
#define M_NODE (B_*N_)   // 20000
#define EPS_ 1e-5f

typedef unsigned short u16;
typedef unsigned int   u32;
typedef __attribute__((ext_vector_type(8))) __bf16 bf16x8;
typedef __attribute__((ext_vector_type(4))) float  f32x4;

__device__ __forceinline__ u16 f2bf(float x) {
  union { float f; u32 u; } v; v.f = x;
  u32 r = v.u + 0x7FFFu + ((v.u >> 16) & 1u);   // RNE
  return (u16)(r >> 16);
}

__device__ __forceinline__ void async16(void* lds, const void* g) {
  __builtin_amdgcn_global_load_lds(
      (const __attribute__((address_space(1))) void*)g,
      (__attribute__((address_space(3))) void*)lds, 16, 0, 0);
}

// ---------------- init: agg sentinels + zero stats ----------------
__global__ void k_init(int* __restrict__ aggmax, int* __restrict__ aggmin,
                       float* __restrict__ stats) {
  int i = blockIdx.x * 256 + threadIdx.x;
  if (i < B_*N_*C_) {
    aggmax[i] = (int)0xBF800000u;   // -1.0f  (y>=0 -> any write beats it)
    aggmin[i] = 0x7F800000;         // +inf
  }
  if (i < 1024) stats[i] = 0.f;     // esum, esumsq, usum, usumsq
}

// ---------------- features [B][C][N] f32 -> vf [B][N][C] bf16 ----------------
__global__ void k_transpose_feat(const float* __restrict__ f, u16* __restrict__ vf) {
  __shared__ float tile[32][33];
  int tx = threadIdx.x & 31, ty = threadIdx.x >> 5;
  int b = blockIdx.z, c0 = blockIdx.y * 32, n0 = blockIdx.x * 32;
  #pragma unroll
  for (int i = 0; i < 4; i++) {
    int c = c0 + ty + i*8, n = n0 + tx;
    tile[ty + i*8][tx] = (n < N_) ? f[((size_t)(b*C_ + c))*N_ + n] : 0.f;
  }
  __syncthreads();
  #pragma unroll
  for (int i = 0; i < 4; i++) {
    int n = n0 + ty + i*8, c = c0 + tx;
    if (n < N_) vf[((size_t)(b*N_ + n))*C_ + c] = f2bf(tile[tx][ty + i*8]);
  }
}

// ---------------- W_e[0:256][:], W_u -> transposed bf16 [Cout][K] ----------------
__global__ void k_transpose_w(const float* __restrict__ We, const float* __restrict__ Wu,
                              u16* __restrict__ WeT, u16* __restrict__ WuT) {
  __shared__ float tile[32][33];
  const float* src = blockIdx.z ? Wu : We;
  u16* dst = blockIdx.z ? WuT : WeT;
  int tx = threadIdx.x & 31, ty = threadIdx.x >> 5;
  int r0 = blockIdx.y * 32, c0 = blockIdx.x * 32;
  #pragma unroll
  for (int i = 0; i < 4; i++)
    tile[ty + i*8][tx] = src[(size_t)(r0 + ty + i*8)*C_ + c0 + tx];
  __syncthreads();
  #pragma unroll
  for (int i = 0; i < 4; i++)
    dst[(size_t)(c0 + ty + i*8)*C_ + r0 + tx] = f2bf(tile[tx][ty + i*8]);
}

// ---------------- edge GEMM: y=relu(ef@We+b); stats + scatter max/min ----------------
__global__ __launch_bounds__(256)
void k_edge(const u16* __restrict__ vf, const u16* __restrict__ WeT,
            const float* __restrict__ We, const float* __restrict__ be,
            const float* __restrict__ ge,
            const int* __restrict__ edges, const float* __restrict__ xyz,
            int* __restrict__ aggmax, int* __restrict__ aggmin,
            float* __restrict__ esum, float* __restrict__ esumsq)
{
  __shared__ __align__(16) u16 As[128*32];
  __shared__ __align__(16) u16 Bs[128*32];
  __shared__ u32 sAOff[128];
  __shared__ u32 sDOff[128];
  __shared__ float sDx[128], sDy[128], sDz[128];

  const int t  = threadIdx.x;
  const int n0 = blockIdx.x * 128;
  const int mb = blockIdx.y * 128;

  if (t < 128) {
    int m  = mb + t;
    int mm = (m < M_EDGE) ? m : 0;
    int b  = (mm >= E_) ? 1 : 0;
    int e  = mm - b * E_;
    int s  = edges[(size_t)(b*2 + 0)*E_ + e];
    int d  = edges[(size_t)(b*2 + 1)*E_ + e];
    sAOff[t] = (u32)(b*N_ + s) * C_;
    sDOff[t] = (u32)(b*N_ + d) * C_;
    const float* ps = xyz + ((size_t)(b*N_ + s))*3;
    const float* pd = xyz + ((size_t)(b*N_ + d))*3;
    sDx[t] = ps[0] - pd[0];
    sDy[t] = ps[1] - pd[1];
    sDz[t] = ps[2] - pd[2];
  }
  __syncthreads();

  const u32 aoff0 = sAOff[t >> 2];
  const u32 aoff1 = sAOff[64 + (t >> 2)];
  const int ak = (((t & 3) ^ ((t >> 3) & 3)) << 3);   // pre-swizzled k-chunk (elems)
  const u16* bsrc0 = WeT + (size_t)(n0 + (t >> 2)) * C_ + ak;
  const u16* bsrc1 = WeT + (size_t)(n0 + 64 + (t >> 2)) * C_ + ak;

  const f32x4 zero = {0.f, 0.f, 0.f, 0.f};
  f32x4 acc[4][4];
  #pragma unroll
  for (int m = 0; m < 4; m++)
    #pragma unroll
    for (int n = 0; n < 4; n++) acc[m][n] = zero;

  const int lane = t & 63, wave = t >> 6;
  const int wr = wave >> 1, wc = wave & 1;
  const int lr = lane & 15, lch = lane >> 4;
  const int swz = (lr >> 1) & 3;

  for (int kk = 0; kk < 8; kk++) {
    const int k0 = kk * 32;
    async16(&As[t*8],         vf + aoff0 + k0 + ak);
    async16(&As[(t+256)*8],   vf + aoff1 + k0 + ak);
    async16(&Bs[t*8],         bsrc0 + k0);
    async16(&Bs[(t+256)*8],   bsrc1 + k0);
    __syncthreads();
    bf16x8 a[4], b[4];
    #pragma unroll
    for (int m = 0; m < 4; m++)
      a[m] = *(const bf16x8*)&As[(wr*64 + m*16 + lr)*32 + ((lch ^ swz) << 3)];
    #pragma unroll
    for (int n = 0; n < 4; n++)
      b[n] = *(const bf16x8*)&Bs[(wc*64 + n*16 + lr)*32 + ((lch ^ swz) << 3)];
    #pragma unroll
    for (int m = 0; m < 4; m++)
      #pragma unroll
      for (int n = 0; n < 4; n++)
        acc[m][n] = __builtin_amdgcn_mfma_f32_16x16x32_bf16(a[m], b[n], acc[m][n], 0, 0, 0);
    __syncthreads();
  }

  // epilogue: +bias +xyz-term (fp32 exact), relu, stats, scatter
  int gc[4]; float bias[4], w0[4], w1[4], w2[4], gs[4];
  #pragma unroll
  for (int n = 0; n < 4; n++) {
    int c = n0 + wc*64 + n*16 + lr;
    gc[n] = c;
    bias[n] = be[c];
    w0[n] = We[256*C_ + c];
    w1[n] = We[257*C_ + c];
    w2[n] = We[258*C_ + c];
    gs[n] = ge[c];
  }
  float psum[4] = {0.f,0.f,0.f,0.f};
  float psq [4] = {0.f,0.f,0.f,0.f};
  #pragma unroll
  for (int m = 0; m < 4; m++) {
    #pragma unroll
    for (int j = 0; j < 4; j++) {
      int r = wr*64 + m*16 + lch*4 + j;
      bool valid = (mb + r) < M_EDGE;
      float dx = sDx[r], dy = sDy[r], dz = sDz[r];
      u32 doff = sDOff[r];
      #pragma unroll
      for (int n = 0; n < 4; n++) {
        float y = acc[m][n][j] + bias[n] + dx*w0[n] + dy*w1[n] + dz*w2[n];
        y = fmaxf(y, 0.f);
        if (valid) {
          psum[n] += y;
          psq[n]  += y*y;
          if (gs[n] >= 0.f) atomicMax(&aggmax[doff + (u32)gc[n]], __float_as_int(y));
          else              atomicMin(&aggmin[doff + (u32)gc[n]], __float_as_int(y));
        }
      }
    }
  }
  #pragma unroll
  for (int n = 0; n < 4; n++) {
    float s1 = psum[n], s2 = psq[n];
    s1 += __shfl_xor(s1, 16, 64);  s2 += __shfl_xor(s2, 16, 64);
    s1 += __shfl_xor(s1, 32, 64);  s2 += __shfl_xor(s2, 32, 64);
    if (lch == 0) { atomicAdd(&esum[gc[n]], s1); atomicAdd(&esumsq[gc[n]], s2); }
  }
}

// ---------------- BN stats -> scale/shift ----------------
__global__ void k_stats(const float* __restrict__ sum, const float* __restrict__ sumsq,
                        const float* __restrict__ g, const float* __restrict__ beta,
                        float cnt, float* __restrict__ scale, float* __restrict__ shift) {
  int c = threadIdx.x;
  float m = sum[c] / cnt;
  float v = sumsq[c] / cnt - m*m;
  v = fmaxf(v, 0.f);
  float s = g[c] * rsqrtf(v + EPS_);
  scale[c] = s;
  shift[c] = beta[c] - m*s;
}

// ---------------- agg -> normalized bf16 (empty segments -> 0) ----------------
__global__ void k_aggnorm(const int* __restrict__ aggmax, const int* __restrict__ aggmin,
                          const float* __restrict__ ge,
                          const float* __restrict__ scale, const float* __restrict__ shift,
                          u32* __restrict__ out) {
  int i = blockIdx.x * 256 + threadIdx.x;       // pair index
  if (i >= B_*N_*C_/2) return;
  int cbase = (i*2) & (C_-1);
  u32 r = 0;
  #pragma unroll
  for (int k = 0; k < 2; k++) {
    int idx = i*2 + k, c = cbase + k;
    float val;
    if (ge[c] >= 0.f) {
      float x = __int_as_float(aggmax[idx]);
      val = (x < 0.f) ? 0.f : fmaf(x, scale[c], shift[c]);
    } else {
      int xb = aggmin[idx];
      val = (xb == 0x7F800000) ? 0.f : fmaf(__int_as_float(xb), scale[c], shift[c]);
    }
    r |= ((u32)f2bf(val)) << (k*16);
  }
  out[i] = r;
}

// ---------------- u GEMM: y=relu(agg@Wu+b); stats; store y ----------------
__global__ __launch_bounds__(256)
void k_ugemm(const u16* __restrict__ A, const u16* __restrict__ WuT,
             const float* __restrict__ bu,
             float* __restrict__ yu, float* __restrict__ usum, float* __restrict__ usumsq)
{
  __shared__ __align__(16) u16 As[128*32];
  __shared__ __align__(16) u16 Bs[128*32];
  const int t  = threadIdx.x;
  const int n0 = blockIdx.x * 128;
  const int mb = blockIdx.y * 128;

  int r0 = mb + (t >> 2);      if (r0 >= M_NODE) r0 = 0;
  int r1 = mb + 64 + (t >> 2); if (r1 >= M_NODE) r1 = 0;
  const int ak = (((t & 3) ^ ((t >> 3) & 3)) << 3);
  const u16* asrc0 = A + (size_t)r0 * C_ + ak;
  const u16* asrc1 = A + (size_t)r1 * C_ + ak;
  const u16* bsrc0 = WuT + (size_t)(n0 + (t >> 2)) * C_ + ak;
  const u16* bsrc1 = WuT + (size_t)(n0 + 64 + (t >> 2)) * C_ + ak;

  const f32x4 zero = {0.f, 0.f, 0.f, 0.f};
  f32x4 acc[4][4];
  #pragma unroll
  for (int m = 0; m < 4; m++)
    #pragma unroll
    for (int n = 0; n < 4; n++) acc[m][n] = zero;

  const int lane = t & 63, wave = t >> 6;
  const int wr = wave >> 1, wc = wave & 1;
  const int lr = lane & 15, lch = lane >> 4;
  const int swz = (lr >> 1) & 3;

  for (int kk = 0; kk < 8; kk++) {
    const int k0 = kk * 32;
    async16(&As[t*8],        asrc0 + k0);
    async16(&As[(t+256)*8],  asrc1 + k0);
    async16(&Bs[t*8],        bsrc0 + k0);
    async16(&Bs[(t+256)*8],  bsrc1 + k0);
    __syncthreads();
    bf16x8 a[4], b[4];
    #pragma unroll
    for (int m = 0; m < 4; m++)
      a[m] = *(const bf16x8*)&As[(wr*64 + m*16 + lr)*32 + ((lch ^ swz) << 3)];
    #pragma unroll
    for (int n = 0; n < 4; n++)
      b[n] = *(const bf16x8*)&Bs[(wc*64 + n*16 + lr)*32 + ((lch ^ swz) << 3)];
    #pragma unroll
    for (int m = 0; m < 4; m++)
      #pragma unroll
      for (int n = 0; n < 4; n++)
        acc[m][n] = __builtin_amdgcn_mfma_f32_16x16x32_bf16(a[m], b[n], acc[m][n], 0, 0, 0);
    __syncthreads();
  }

  int gc[4]; float bias[4];
  #pragma unroll
  for (int n = 0; n < 4; n++) { int c = n0 + wc*64 + n*16 + lr; gc[n] = c; bias[n] = bu[c]; }
  float psum[4] = {0.f,0.f,0.f,0.f};
  float psq [4] = {0.f,0.f,0.f,0.f};
  #pragma unroll
  for (int m = 0; m < 4; m++) {
    #pragma unroll
    for (int j = 0; j < 4; j++) {
      int r = mb + wr*64 + m*16 + lch*4 + j;
      bool valid = r < M_NODE;
      #pragma unroll
      for (int n = 0; n < 4; n++) {
        float y = fmaxf(acc[m][n][j] + bias[n], 0.f);
        if (valid) {
          psum[n] += y;
          psq[n]  += y*y;
          yu[(size_t)r * C_ + gc[n]] = y;
        }
      }
    }
  }
  #pragma unroll
  for (int n = 0; n < 4; n++) {
    float s1 = psum[n], s2 = psq[n];
    s1 += __shfl_xor(s1, 16, 64);  s2 += __shfl_xor(s2, 16, 64);
    s1 += __shfl_xor(s1, 32, 64);  s2 += __shfl_xor(s2, 32, 64);
    if (lch == 0) { atomicAdd(&usum[gc[n]], s1); atomicAdd(&usumsq[gc[n]], s2); }
  }
}

// ---------------- final: BN affine + residual + transpose to [B][C][N] ----------------
__global__ void k_final(const float* __restrict__ yu, const float* __restrict__ feat,
                        const float* __restrict__ scale, const float* __restrict__ shift,
                        float* __restrict__ out) {
  __shared__ float tile[32][33];
  int tx = threadIdx.x & 31, ty = threadIdx.x >> 5;
  int b = blockIdx.z, c0 = blockIdx.y * 32, n0 = blockIdx.x * 32;
  #pragma unroll
  for (int i = 0; i < 4; i++) {
    int n = n0 + ty + i*8;
    tile[ty + i*8][tx] = (n < N_) ? yu[((size_t)(b*N_ + n))*C_ + c0 + tx] : 0.f;
  }
  __syncthreads();
  int n = n0 + tx;
  if (n < N_) {
    #pragma unroll
    for (int i = 0; i < 4; i++) {
      int c = c0 + ty + i*8;
      float v = tile[tx][ty + i*8] * scale[c] + shift[c];
      out[((size_t)(b*C_ + c))*N_ + n] = v + feat[((size_t)(b*C_ + c))*N_ + n];
    }
  }
}

extern "C" void kernel_launch(void* const* d_in, const int* in_sizes, int n_in,
                              void* d_out, int out_size, void* d_ws, size_t ws_size,
                              hipStream_t stream) {
  const float* xyz  = (const float*)d_in[0];
  const float* feat = (const float*)d_in[1];
  const int*   edges= (const int*)  d_in[2];
  const float* We   = (const float*)d_in[3];
  const float* be   = (const float*)d_in[4];
  const float* ge   = (const float*)d_in[5];
  const float* bte  = (const float*)d_in[6];
  const float* Wu   = (const float*)d_in[7];
  const float* bu   = (const float*)d_in[8];
  const float* gu   = (const float*)d_in[9];
  const float* btu  = (const float*)d_in[10];
  float* out = (float*)d_out;

  char* w = (char*)d_ws;
  size_t off = 0;
  auto carve = [&](size_t bytes) -> void* {
    void* p = w + off;
    off = (off + bytes + 511) & ~(size_t)511;
    return p;
  };
  u16*  vf      = (u16*) carve((size_t)B_*N_*C_*2);
  u16*  WeT     = (u16*) carve((size_t)C_*C_*2);
  u16*  WuT     = (u16*) carve((size_t)C_*C_*2);
  int*  aggmax  = (int*) carve((size_t)B_*N_*C_*4);
  int*  aggmin  = (int*) carve((size_t)B_*N_*C_*4);
  u32*  aggnorm = (u32*) carve((size_t)B_*N_*C_*2);
  float* yu     = (float*)carve((size_t)M_NODE*C_*4);
  float* stats  = (float*)carve(2048*4);
  float* esum = stats,        *esumsq = stats + 256;
  float* usum = stats + 512,  *usumsq = stats + 768;
  float* scale_e = stats + 1024, *shift_e = stats + 1280;
  float* scale_u = stats + 1536, *shift_u = stats + 1792;

  k_init<<<dim3((B_*N_*C_ + 255)/256), 256, 0, stream>>>(aggmax, aggmin, stats);
  k_transpose_feat<<<dim3((N_+31)/32, C_/32, B_), 256, 0, stream>>>(feat, vf);
  k_transpose_w<<<dim3(C_/32, C_/32, 2), 256, 0, stream>>>(We, Wu, WeT, WuT);
  k_edge<<<dim3(2, (M_EDGE + 127)/128), 256, 0, stream>>>(
      vf, WeT, We, be, ge, edges, xyz, aggmax, aggmin, esum, esumsq);
  k_stats<<<1, 256, 0, stream>>>(esum, esumsq, ge, bte, (float)M_EDGE, scale_e, shift_e);
  k_aggnorm<<<dim3(B_*N_*C_/512), 256, 0, stream>>>(aggmax, aggmin, ge, scale_e, shift_e, aggnorm);
  k_ugemm<<<dim3(2, (M_NODE + 127)/128), 256, 0, stream>>>(
      (const u16*)aggnorm, WuT, bu, yu, usum, usumsq);
  k_stats<<<1, 256, 0, stream>>>(usum, usumsq, gu, btu, (float)M_NODE, scale_u, shift_u);
  k_final<<<dim3((N_+31)/32, C_/32, B_), 256, 0, stream>>>(yu, feat, scale_u, shift_u, out);
}

// Round 2
// 228.039 us; speedup vs baseline: 1.7060x; 1.7060x over previous
//
#include <hip/hip_runtime.h>

#define B_ 2
#define N_ 10000
#define E_ 150000
#define C_ 256
#define M_EDGE (B_*E_)   // 300000
#define M_NODE (B_*N_)   // 20000
#define EPS_ 1e-5f

typedef unsigned short u16;
typedef unsigned int   u32;
typedef __attribute__((ext_vector_type(8))) __bf16 bf16x8;
typedef __attribute__((ext_vector_type(4))) float  f32x4;

__device__ __forceinline__ u16 f2bf(float x) {
  union { float f; u32 u; } v; v.f = x;
  u32 r = v.u + 0x7FFFu + ((v.u >> 16) & 1u);   // RNE
  return (u16)(r >> 16);
}

__device__ __forceinline__ void async16(void* lds, const void* g) {
  __builtin_amdgcn_global_load_lds(
      (const __attribute__((address_space(1))) void*)g,
      (__attribute__((address_space(3))) void*)lds, 16, 0, 0);
}

// ---------------- init: zero counts + stats ----------------
__global__ void k_init(int* __restrict__ counts, float* __restrict__ stats) {
  int i = blockIdx.x * 256 + threadIdx.x;
  if (i < M_NODE) counts[i] = 0;
  if (i < 1024) stats[i] = 0.f;
}

// ---------------- features [B][C][N] f32 -> vf [B][N][C] bf16 ----------------
__global__ void k_transpose_feat(const float* __restrict__ f, u16* __restrict__ vf) {
  __shared__ float tile[32][33];
  int tx = threadIdx.x & 31, ty = threadIdx.x >> 5;
  int b = blockIdx.z, c0 = blockIdx.y * 32, n0 = blockIdx.x * 32;
  #pragma unroll
  for (int i = 0; i < 4; i++) {
    int c = c0 + ty + i*8, n = n0 + tx;
    tile[ty + i*8][tx] = (n < N_) ? f[((size_t)(b*C_ + c))*N_ + n] : 0.f;
  }
  __syncthreads();
  #pragma unroll
  for (int i = 0; i < 4; i++) {
    int n = n0 + ty + i*8, c = c0 + tx;
    if (n < N_) vf[((size_t)(b*N_ + n))*C_ + c] = f2bf(tile[tx][ty + i*8]);
  }
}

// ---------------- W_e[0:256][:], W_u -> transposed bf16 [Cout][K] ----------------
__global__ void k_transpose_w(const float* __restrict__ We, const float* __restrict__ Wu,
                              u16* __restrict__ WeT, u16* __restrict__ WuT) {
  __shared__ float tile[32][33];
  const float* src = blockIdx.z ? Wu : We;
  u16* dst = blockIdx.z ? WuT : WeT;
  int tx = threadIdx.x & 31, ty = threadIdx.x >> 5;
  int r0 = blockIdx.y * 32, c0 = blockIdx.x * 32;
  #pragma unroll
  for (int i = 0; i < 4; i++)
    tile[ty + i*8][tx] = src[(size_t)(r0 + ty + i*8)*C_ + c0 + tx];
  __syncthreads();
  #pragma unroll
  for (int i = 0; i < 4; i++)
    dst[(size_t)(c0 + ty + i*8)*C_ + r0 + tx] = f2bf(tile[tx][ty + i*8]);
}

// ---------------- histogram of dst ----------------
__global__ void k_hist(const int* __restrict__ edges, int* __restrict__ counts) {
  int i = blockIdx.x * 256 + threadIdx.x;
  if (i >= M_EDGE) return;
  int b = (i >= E_) ? 1 : 0;
  int e = i - b * E_;
  int d = edges[(size_t)(b*2 + 1)*E_ + e];
  atomicAdd(&counts[b*N_ + d], 1);
}

// ---------------- exclusive scan of counts (single block) ----------------
__global__ __launch_bounds__(1024)
void k_scan(const int* __restrict__ counts, int* __restrict__ offs, int* __restrict__ cursor) {
  __shared__ int part[1024];
  int t = threadIdx.x;
  int base = t * 20;
  int local[20];
  int s = 0;
  #pragma unroll
  for (int i = 0; i < 20; i++) {
    int v = (base + i < M_NODE) ? counts[base + i] : 0;
    local[i] = s; s += v;
  }
  part[t] = s;
  __syncthreads();
  for (int d = 1; d < 1024; d <<= 1) {
    int v = (t >= d) ? part[t - d] : 0;
    __syncthreads();
    part[t] += v;
    __syncthreads();
  }
  int excl = (t == 0) ? 0 : part[t - 1];
  #pragma unroll
  for (int i = 0; i < 20; i++) {
    if (base + i < M_NODE) {
      int o = excl + local[i];
      offs[base + i] = o;
      cursor[base + i] = o;
    }
  }
}

// ---------------- scatter edges into CSR slots (packed descriptor) ----------------
__global__ void k_scatter(const int* __restrict__ edges, const float* __restrict__ xyz,
                          int* __restrict__ cursor, float4* __restrict__ ed) {
  int i = blockIdx.x * 256 + threadIdx.x;
  if (i >= M_EDGE) return;
  int b = (i >= E_) ? 1 : 0;
  int e = i - b * E_;
  int s = edges[(size_t)(b*2 + 0)*E_ + e];
  int d = edges[(size_t)(b*2 + 1)*E_ + e];
  const float* ps = xyz + ((size_t)(b*N_ + s))*3;
  const float* pd = xyz + ((size_t)(b*N_ + d))*3;
  int pos = atomicAdd(&cursor[b*N_ + d], 1);
  ed[pos] = make_float4(ps[0]-pd[0], ps[1]-pd[1], ps[2]-pd[2],
                        __int_as_float(b*N_ + s));
}

// ---------------- z GEMM: z = vf @ We[0:256] + be (f32 out) ----------------
__global__ __launch_bounds__(256)
void k_zgemm(const u16* __restrict__ A, const u16* __restrict__ WeT,
             const float* __restrict__ be, float* __restrict__ z)
{
  __shared__ __align__(16) u16 As[128*32];
  __shared__ __align__(16) u16 Bs[128*32];
  const int t  = threadIdx.x;
  const int n0 = blockIdx.x * 128;
  const int mb = blockIdx.y * 128;

  int r0 = mb + (t >> 2);      if (r0 >= M_NODE) r0 = 0;
  int r1 = mb + 64 + (t >> 2); if (r1 >= M_NODE) r1 = 0;
  const int ak = (((t & 3) ^ ((t >> 3) & 3)) << 3);
  const u16* asrc0 = A + (size_t)r0 * C_ + ak;
  const u16* asrc1 = A + (size_t)r1 * C_ + ak;
  const u16* bsrc0 = WeT + (size_t)(n0 + (t >> 2)) * C_ + ak;
  const u16* bsrc1 = WeT + (size_t)(n0 + 64 + (t >> 2)) * C_ + ak;

  const f32x4 zero = {0.f, 0.f, 0.f, 0.f};
  f32x4 acc[4][4];
  #pragma unroll
  for (int m = 0; m < 4; m++)
    #pragma unroll
    for (int n = 0; n < 4; n++) acc[m][n] = zero;

  const int lane = t & 63, wave = t >> 6;
  const int wr = wave >> 1, wc = wave & 1;
  const int lr = lane & 15, lch = lane >> 4;
  const int swz = (lr >> 1) & 3;

  for (int kk = 0; kk < 8; kk++) {
    const int k0 = kk * 32;
    async16(&As[t*8],        asrc0 + k0);
    async16(&As[(t+256)*8],  asrc1 + k0);
    async16(&Bs[t*8],        bsrc0 + k0);
    async16(&Bs[(t+256)*8],  bsrc1 + k0);
    __syncthreads();
    bf16x8 a[4], b[4];
    #pragma unroll
    for (int m = 0; m < 4; m++)
      a[m] = *(const bf16x8*)&As[(wr*64 + m*16 + lr)*32 + ((lch ^ swz) << 3)];
    #pragma unroll
    for (int n = 0; n < 4; n++)
      b[n] = *(const bf16x8*)&Bs[(wc*64 + n*16 + lr)*32 + ((lch ^ swz) << 3)];
    #pragma unroll
    for (int m = 0; m < 4; m++)
      #pragma unroll
      for (int n = 0; n < 4; n++)
        acc[m][n] = __builtin_amdgcn_mfma_f32_16x16x32_bf16(a[m], b[n], acc[m][n], 0, 0, 0);
    __syncthreads();
  }

  int gc[4]; float bias[4];
  #pragma unroll
  for (int n = 0; n < 4; n++) { int c = n0 + wc*64 + n*16 + lr; gc[n] = c; bias[n] = be[c]; }
  #pragma unroll
  for (int m = 0; m < 4; m++) {
    #pragma unroll
    for (int j = 0; j < 4; j++) {
      int r = mb + wr*64 + m*16 + lch*4 + j;
      if (r < M_NODE) {
        #pragma unroll
        for (int n = 0; n < 4; n++)
          z[(size_t)r * C_ + gc[n]] = acc[m][n][j] + bias[n];
      }
    }
  }
}

// ---------------- aggregation: per-node edge walk, reg max/min, BN-e stats ----------------
__global__ __launch_bounds__(256)
void k_agg(const float* __restrict__ z, const float4* __restrict__ ed,
           const int* __restrict__ offs, const int* __restrict__ counts,
           const float* __restrict__ We, const float* __restrict__ ge,
           float* __restrict__ agg, float* __restrict__ esum, float* __restrict__ esumsq)
{
  const int lane = threadIdx.x & 63, wave = threadIdx.x >> 6;
  const int c0 = lane * 4;
  const float4 w0 = *(const float4*)&We[256*C_ + c0];
  const float4 w1 = *(const float4*)&We[257*C_ + c0];
  const float4 w2 = *(const float4*)&We[258*C_ + c0];
  const float4 gs = *(const float4*)&ge[c0];

  float ps[4] = {0.f,0.f,0.f,0.f};
  float pq[4] = {0.f,0.f,0.f,0.f};

  const int totalWaves = gridDim.x * 4;
  for (int n = blockIdx.x * 4 + wave; n < M_NODE; n += totalWaves) {
    const int start = offs[n], cnt = counts[n];
    float mx[4] = {-1.f,-1.f,-1.f,-1.f};          // y >= 0
    float mn[4] = {1e30f,1e30f,1e30f,1e30f};
    float4 dd;
    if (cnt > 0) dd = ed[start];
    for (int i = 0; i < cnt; i++) {
      float4 cur = dd;
      if (i + 1 < cnt) dd = ed[start + i + 1];    // prefetch next descriptor
      int si = __float_as_int(cur.w);
      const float4 zv = *(const float4*)&z[(size_t)si * C_ + c0];
      float y0 = fmaxf(fmaf(cur.z, w2.x, fmaf(cur.y, w1.x, fmaf(cur.x, w0.x, zv.x))), 0.f);
      float y1 = fmaxf(fmaf(cur.z, w2.y, fmaf(cur.y, w1.y, fmaf(cur.x, w0.y, zv.y))), 0.f);
      float y2 = fmaxf(fmaf(cur.z, w2.z, fmaf(cur.y, w1.z, fmaf(cur.x, w0.z, zv.z))), 0.f);
      float y3 = fmaxf(fmaf(cur.z, w2.w, fmaf(cur.y, w1.w, fmaf(cur.x, w0.w, zv.w))), 0.f);
      mx[0] = fmaxf(mx[0], y0); mn[0] = fminf(mn[0], y0); ps[0] += y0; pq[0] += y0*y0;
      mx[1] = fmaxf(mx[1], y1); mn[1] = fminf(mn[1], y1); ps[1] += y1; pq[1] += y1*y1;
      mx[2] = fmaxf(mx[2], y2); mn[2] = fminf(mn[2], y2); ps[2] += y2; pq[2] += y2*y2;
      mx[3] = fmaxf(mx[3], y3); mn[3] = fminf(mn[3], y3); ps[3] += y3; pq[3] += y3*y3;
    }
    float4 outv;
    outv.x = (gs.x >= 0.f) ? mx[0] : mn[0];
    outv.y = (gs.y >= 0.f) ? mx[1] : mn[1];
    outv.z = (gs.z >= 0.f) ? mx[2] : mn[2];
    outv.w = (gs.w >= 0.f) ? mx[3] : mn[3];
    *(float4*)&agg[(size_t)n * C_ + c0] = outv;   // plain coalesced store
  }

  // block-level stats reduction (4 waves share cols) -> one atomicAdd per col
  __shared__ float red[4][256];
  #pragma unroll
  for (int j = 0; j < 4; j++) red[wave][c0 + j] = ps[j];
  __syncthreads();
  if (threadIdx.x < 256) {
    float s = red[0][threadIdx.x] + red[1][threadIdx.x] + red[2][threadIdx.x] + red[3][threadIdx.x];
    atomicAdd(&esum[threadIdx.x], s);
  }
  __syncthreads();
  #pragma unroll
  for (int j = 0; j < 4; j++) red[wave][c0 + j] = pq[j];
  __syncthreads();
  if (threadIdx.x < 256) {
    float s = red[0][threadIdx.x] + red[1][threadIdx.x] + red[2][threadIdx.x] + red[3][threadIdx.x];
    atomicAdd(&esumsq[threadIdx.x], s);
  }
}

// ---------------- BN stats -> scale/shift ----------------
__global__ void k_stats(const float* __restrict__ sum, const float* __restrict__ sumsq,
                        const float* __restrict__ g, const float* __restrict__ beta,
                        float cnt, float* __restrict__ scale, float* __restrict__ shift) {
  int c = threadIdx.x;
  float m = sum[c] / cnt;
  float v = sumsq[c] / cnt - m*m;
  v = fmaxf(v, 0.f);
  float s = g[c] * rsqrtf(v + EPS_);
  scale[c] = s;
  shift[c] = beta[c] - m*s;
}

// ---------------- agg -> normalized bf16 (empty segments -> 0) ----------------
__global__ void k_aggnorm(const float* __restrict__ agg, const int* __restrict__ counts,
                          const float* __restrict__ scale, const float* __restrict__ shift,
                          u32* __restrict__ out) {
  int i = blockIdx.x * 256 + threadIdx.x;       // pair index
  if (i >= M_NODE*C_/2) return;
  int n = (i*2) >> 8;
  int cbase = (i*2) & (C_-1);
  int cnt = counts[n];
  u32 r = 0;
  #pragma unroll
  for (int k = 0; k < 2; k++) {
    float val = (cnt > 0) ? fmaf(agg[(size_t)i*2 + k], scale[cbase + k], shift[cbase + k]) : 0.f;
    r |= ((u32)f2bf(val)) << (k*16);
  }
  out[i] = r;
}

// ---------------- u GEMM: y=relu(agg@Wu+b); stats; store y ----------------
__global__ __launch_bounds__(256)
void k_ugemm(const u16* __restrict__ A, const u16* __restrict__ WuT,
             const float* __restrict__ bu,
             float* __restrict__ yu, float* __restrict__ usum, float* __restrict__ usumsq)
{
  __shared__ __align__(16) u16 As[128*32];
  __shared__ __align__(16) u16 Bs[128*32];
  const int t  = threadIdx.x;
  const int n0 = blockIdx.x * 128;
  const int mb = blockIdx.y * 128;

  int r0 = mb + (t >> 2);      if (r0 >= M_NODE) r0 = 0;
  int r1 = mb + 64 + (t >> 2); if (r1 >= M_NODE) r1 = 0;
  const int ak = (((t & 3) ^ ((t >> 3) & 3)) << 3);
  const u16* asrc0 = A + (size_t)r0 * C_ + ak;
  const u16* asrc1 = A + (size_t)r1 * C_ + ak;
  const u16* bsrc0 = WuT + (size_t)(n0 + (t >> 2)) * C_ + ak;
  const u16* bsrc1 = WuT + (size_t)(n0 + 64 + (t >> 2)) * C_ + ak;

  const f32x4 zero = {0.f, 0.f, 0.f, 0.f};
  f32x4 acc[4][4];
  #pragma unroll
  for (int m = 0; m < 4; m++)
    #pragma unroll
    for (int n = 0; n < 4; n++) acc[m][n] = zero;

  const int lane = t & 63, wave = t >> 6;
  const int wr = wave >> 1, wc = wave & 1;
  const int lr = lane & 15, lch = lane >> 4;
  const int swz = (lr >> 1) & 3;

  for (int kk = 0; kk < 8; kk++) {
    const int k0 = kk * 32;
    async16(&As[t*8],        asrc0 + k0);
    async16(&As[(t+256)*8],  asrc1 + k0);
    async16(&Bs[t*8],        bsrc0 + k0);
    async16(&Bs[(t+256)*8],  bsrc1 + k0);
    __syncthreads();
    bf16x8 a[4], b[4];
    #pragma unroll
    for (int m = 0; m < 4; m++)
      a[m] = *(const bf16x8*)&As[(wr*64 + m*16 + lr)*32 + ((lch ^ swz) << 3)];
    #pragma unroll
    for (int n = 0; n < 4; n++)
      b[n] = *(const bf16x8*)&Bs[(wc*64 + n*16 + lr)*32 + ((lch ^ swz) << 3)];
    #pragma unroll
    for (int m = 0; m < 4; m++)
      #pragma unroll
      for (int n = 0; n < 4; n++)
        acc[m][n] = __builtin_amdgcn_mfma_f32_16x16x32_bf16(a[m], b[n], acc[m][n], 0, 0, 0);
    __syncthreads();
  }

  int gc[4]; float bias[4];
  #pragma unroll
  for (int n = 0; n < 4; n++) { int c = n0 + wc*64 + n*16 + lr; gc[n] = c; bias[n] = bu[c]; }
  float psum[4] = {0.f,0.f,0.f,0.f};
  float psq [4] = {0.f,0.f,0.f,0.f};
  #pragma unroll
  for (int m = 0; m < 4; m++) {
    #pragma unroll
    for (int j = 0; j < 4; j++) {
      int r = mb + wr*64 + m*16 + lch*4 + j;
      bool valid = r < M_NODE;
      #pragma unroll
      for (int n = 0; n < 4; n++) {
        float y = fmaxf(acc[m][n][j] + bias[n], 0.f);
        if (valid) {
          psum[n] += y;
          psq[n]  += y*y;
          yu[(size_t)r * C_ + gc[n]] = y;
        }
      }
    }
  }
  #pragma unroll
  for (int n = 0; n < 4; n++) {
    float s1 = psum[n], s2 = psq[n];
    s1 += __shfl_xor(s1, 16, 64);  s2 += __shfl_xor(s2, 16, 64);
    s1 += __shfl_xor(s1, 32, 64);  s2 += __shfl_xor(s2, 32, 64);
    if (lch == 0) { atomicAdd(&usum[gc[n]], s1); atomicAdd(&usumsq[gc[n]], s2); }
  }
}

// ---------------- final: BN affine + residual + transpose to [B][C][N] ----------------
__global__ void k_final(const float* __restrict__ yu, const float* __restrict__ feat,
                        const float* __restrict__ scale, const float* __restrict__ shift,
                        float* __restrict__ out) {
  __shared__ float tile[32][33];
  int tx = threadIdx.x & 31, ty = threadIdx.x >> 5;
  int b = blockIdx.z, c0 = blockIdx.y * 32, n0 = blockIdx.x * 32;
  #pragma unroll
  for (int i = 0; i < 4; i++) {
    int n = n0 + ty + i*8;
    tile[ty + i*8][tx] = (n < N_) ? yu[((size_t)(b*N_ + n))*C_ + c0 + tx] : 0.f;
  }
  __syncthreads();
  int n = n0 + tx;
  if (n < N_) {
    #pragma unroll
    for (int i = 0; i < 4; i++) {
      int c = c0 + ty + i*8;
      float v = tile[tx][ty + i*8] * scale[c] + shift[c];
      out[((size_t)(b*C_ + c))*N_ + n] = v + feat[((size_t)(b*C_ + c))*N_ + n];
    }
  }
}

extern "C" void kernel_launch(void* const* d_in, const int* in_sizes, int n_in,
                              void* d_out, int out_size, void* d_ws, size_t ws_size,
                              hipStream_t stream) {
  const float* xyz  = (const float*)d_in[0];
  const float* feat = (const float*)d_in[1];
  const int*   edges= (const int*)  d_in[2];
  const float* We   = (const float*)d_in[3];
  const float* be   = (const float*)d_in[4];
  const float* ge   = (const float*)d_in[5];
  const float* bte  = (const float*)d_in[6];
  const float* Wu   = (const float*)d_in[7];
  const float* bu   = (const float*)d_in[8];
  const float* gu   = (const float*)d_in[9];
  const float* btu  = (const float*)d_in[10];
  float* out = (float*)d_out;

  char* w = (char*)d_ws;
  size_t off = 0;
  auto carve = [&](size_t bytes) -> void* {
    void* p = w + off;
    off = (off + bytes + 511) & ~(size_t)511;
    return p;
  };
  u16*  vf      = (u16*) carve((size_t)M_NODE*C_*2);       // 10.24 MB
  u16*  WeT     = (u16*) carve((size_t)C_*C_*2);
  u16*  WuT     = (u16*) carve((size_t)C_*C_*2);
  float* z      = (float*)carve((size_t)M_NODE*C_*4);      // 20.48 MB
  float4* ed    = (float4*)carve((size_t)M_EDGE*16);       // 4.8 MB
  int*  counts  = (int*) carve((size_t)M_NODE*4);
  int*  offs    = (int*) carve((size_t)M_NODE*4);
  int*  cursor  = (int*) carve((size_t)M_NODE*4);
  float* agg    = (float*)carve((size_t)M_NODE*C_*4);      // 20.48 MB
  u32*  aggnorm = (u32*) carve((size_t)M_NODE*C_*2);       // 10.24 MB
  float* yu     = (float*)carve((size_t)M_NODE*C_*4);      // 20.48 MB
  float* stats  = (float*)carve(2048*4);
  float* esum = stats,        *esumsq = stats + 256;
  float* usum = stats + 512,  *usumsq = stats + 768;
  float* scale_e = stats + 1024, *shift_e = stats + 1280;
  float* scale_u = stats + 1536, *shift_u = stats + 1792;

  k_init<<<dim3((M_NODE + 255)/256), 256, 0, stream>>>(counts, stats);
  k_transpose_feat<<<dim3((N_+31)/32, C_/32, B_), 256, 0, stream>>>(feat, vf);
  k_transpose_w<<<dim3(C_/32, C_/32, 2), 256, 0, stream>>>(We, Wu, WeT, WuT);
  k_hist<<<dim3((M_EDGE + 255)/256), 256, 0, stream>>>(edges, counts);
  k_scan<<<1, 1024, 0, stream>>>(counts, offs, cursor);
  k_scatter<<<dim3((M_EDGE + 255)/256), 256, 0, stream>>>(edges, xyz, cursor, ed);
  k_zgemm<<<dim3(2, (M_NODE + 127)/128), 256, 0, stream>>>(vf, WeT, be, z);
  k_agg<<<dim3(2500), 256, 0, stream>>>(z, ed, offs, counts, We, ge, agg, esum, esumsq);
  k_stats<<<1, 256, 0, stream>>>(esum, esumsq, ge, bte, (float)M_EDGE, scale_e, shift_e);
  k_aggnorm<<<dim3(M_NODE*C_/512), 256, 0, stream>>>(agg, counts, scale_e, shift_e, aggnorm);
  k_ugemm<<<dim3(2, (M_NODE + 127)/128), 256, 0, stream>>>(
      (const u16*)aggnorm, WuT, bu, yu, usum, usumsq);
  k_stats<<<1, 256, 0, stream>>>(usum, usumsq, gu, btu, (float)M_NODE, scale_u, shift_u);
  k_final<<<dim3((N_+31)/32, C_/32, B_), 256, 0, stream>>>(yu, feat, scale_u, shift_u, out);
}